// Round 1
// baseline (2309.190 us; speedup 1.0000x reference)
//
#include <hip/hip_runtime.h>

// GCLSDA encoder: ego=concat(U,I); 3x { ego = A@ego; ego += sign(ego)*nhat*0.1; acc+=ego }
// Outputs: final=acc/3 (d_out[0:12.8M]), cl=ego_layer1 (d_out[12.8M:25.6M]).
// Correctness strategy: bitwise-match numpy reference.
//  - SpMM: stable CSR (within-row ascending edge index) + sequential per-(row,dim)
//    accumulation with separate _rn mul/add => identical to np.add.at order.
//  - Row norm: numpy pairwise_sum 8-accumulator pattern for n=64, exact.
//  - No atomics in any FP accumulation.

#define USER_NUM 100000
#define N_NODES  200000
#define EMB      64
#define N_EDGES  6400000

// ---- workspace layout (bytes, all 16-aligned) ----
// bufA: 51,200,000   (ego ping)
// bufB: 51,200,000   (ego pong; first 25.6MB aliased as perm[] during CSR build)
// cv:   51,200,000   (int2 {col, val_bits} per edge, row-sorted stable)
// rs:   800,016      (row_start[200001])
// fill: 800,000      (histogram / scatter cursors)
// nrm:  800,000      (per-row noise norms; aliased as bsum[] during scan)
static constexpr size_t BUFA_OFF = 0;
static constexpr size_t BUFB_OFF = 51200000;
static constexpr size_t CV_OFF   = 102400000;
static constexpr size_t RS_OFF   = 153600000;
static constexpr size_t FILL_OFF = 154400016;
static constexpr size_t NRM_OFF  = 155200016;
static constexpr size_t WS_NEED  = 156000016;

__global__ void k_hist(const int* __restrict__ rows, int* __restrict__ cnt) {
    int e = blockIdx.x * blockDim.x + threadIdx.x;
    if (e < N_EDGES) atomicAdd(&cnt[rows[e]], 1);
}

__global__ void k_scan1(const int* __restrict__ cnt, int* __restrict__ rs,
                        int* __restrict__ bsum) {
    __shared__ int s[1024];
    int i = blockIdx.x * 1024 + threadIdx.x;
    int v = (i < N_NODES) ? cnt[i] : 0;
    s[threadIdx.x] = v;
    __syncthreads();
    for (int off = 1; off < 1024; off <<= 1) {
        int t = 0;
        if ((int)threadIdx.x >= off) t = s[threadIdx.x - off];
        __syncthreads();
        s[threadIdx.x] += t;
        __syncthreads();
    }
    if (i < N_NODES) rs[i] = s[threadIdx.x] - v;  // exclusive
    if (threadIdx.x == 1023) bsum[blockIdx.x] = s[1023];
}

__global__ void k_scan2(int* __restrict__ bsum, int nb) {
    if (blockIdx.x == 0 && threadIdx.x == 0) {
        int run = 0;
        for (int b = 0; b < nb; ++b) { int v = bsum[b]; bsum[b] = run; run += v; }
    }
}

__global__ void k_scan3(int* __restrict__ rs, const int* __restrict__ bsum) {
    int i = blockIdx.x * blockDim.x + threadIdx.x;
    if (i < N_NODES) rs[i] += bsum[i >> 10];
    if (i == 0) rs[N_NODES] = N_EDGES;
}

__global__ void k_scatter(const int* __restrict__ rows, const int* __restrict__ rs,
                          int* __restrict__ cur, int* __restrict__ perm) {
    int e = blockIdx.x * blockDim.x + threadIdx.x;
    if (e < N_EDGES) {
        int r = rows[e];
        int p = rs[r] + atomicAdd(&cur[r], 1);
        perm[p] = e;
    }
}

__global__ void k_sort(const int* __restrict__ rs, int* __restrict__ perm) {
    int r = blockIdx.x * blockDim.x + threadIdx.x;
    if (r >= N_NODES) return;
    int j0 = rs[r], j1 = rs[r + 1];
    for (int i = j0 + 1; i < j1; ++i) {
        int key = perm[i];
        int k = i - 1;
        while (k >= j0) {
            int pk = perm[k];
            if (pk <= key) break;
            perm[k + 1] = pk;
            --k;
        }
        perm[k + 1] = key;
    }
}

__global__ void k_gather(const int* __restrict__ perm, const int* __restrict__ cols,
                         const float* __restrict__ vals, int2* __restrict__ cv) {
    int j = blockIdx.x * blockDim.x + threadIdx.x;
    if (j < N_EDGES) {
        int e = perm[j];
        cv[j] = make_int2(cols[e], __float_as_int(vals[e]));
    }
}

// SpMM: one thread per (row, 4-dim group). Sequential ascending-edge accumulation
// per output element => bitwise np.add.at order. 1-deep software prefetch.
__global__ void k_spmm(const int* __restrict__ rs, const int2* __restrict__ cv,
                       const float* __restrict__ x, float* __restrict__ y) {
    int t = blockIdx.x * blockDim.x + threadIdx.x;
    if (t >= N_NODES * 16) return;
    int r = t >> 4;
    int c = (t & 15) << 2;
    int j0 = rs[r], j1 = rs[r + 1];
    float a0 = 0.f, a1 = 0.f, a2 = 0.f, a3 = 0.f;
    if (j0 < j1) {
        int2 cvc = cv[j0];
        float4 xv = *(const float4*)(x + cvc.x * EMB + c);
        for (int j = j0; j < j1; ++j) {
            int2 cvn = cvc;
            float4 xn = xv;
            if (j + 1 < j1) {
                cvn = cv[j + 1];
                xn = *(const float4*)(x + cvn.x * EMB + c);
            }
            float v = __int_as_float(cvc.y);
            a0 = __fadd_rn(a0, __fmul_rn(v, xv.x));
            a1 = __fadd_rn(a1, __fmul_rn(v, xv.y));
            a2 = __fadd_rn(a2, __fmul_rn(v, xv.z));
            a3 = __fadd_rn(a3, __fmul_rn(v, xv.w));
            cvc = cvn;
            xv = xn;
        }
    }
    *(float4*)(y + r * EMB + c) = make_float4(a0, a1, a2, a3);
}

// Per-row L2 norm of noise, numpy pairwise_sum order (8 accumulators, n=64).
// Block = 128 threads = 2 waves; each wave owns a 64-row LDS tile (pad 65).
__global__ void k_norm(const float* __restrict__ nk, float* __restrict__ nrm) {
    __shared__ float tile[2][64 * 65];
    int wave = threadIdx.x >> 6;
    int lane = threadIdx.x & 63;
    int base = blockIdx.x * 128 + wave * 64;
    for (int rr = 0; rr < 64; ++rr) {
        int row = base + rr;
        float v = 0.f;
        if (row < N_NODES) v = nk[row * EMB + lane];
        tile[wave][rr * 65 + lane] = v;
    }
    __syncthreads();
    int row = base + lane;
    if (row < N_NODES) {
        const float* tp = &tile[wave][lane * 65];
        float rj[8];
        #pragma unroll
        for (int j = 0; j < 8; ++j) {
            float xj = tp[j];
            rj[j] = __fmul_rn(xj, xj);
        }
        #pragma unroll
        for (int i = 8; i < 64; i += 8) {
            #pragma unroll
            for (int j = 0; j < 8; ++j) {
                float xj = tp[i + j];
                rj[j] = __fadd_rn(rj[j], __fmul_rn(xj, xj));
            }
        }
        float s01 = __fadd_rn(rj[0], rj[1]);
        float s23 = __fadd_rn(rj[2], rj[3]);
        float s45 = __fadd_rn(rj[4], rj[5]);
        float s67 = __fadd_rn(rj[6], rj[7]);
        float ss = __fadd_rn(__fadd_rn(s01, s23), __fadd_rn(s45, s67));
        float nv = __fsqrt_rn(ss);
        nv = fmaxf(nv, 1e-12f);
        nrm[row] = nv;
    }
}

// Epilogue: ego = y + (sign(y)*(nk/nrm))*0.1 ; acc update; cl capture (layer 0).
// mode 0: acc=ego, cl=ego.  mode 1: acc+=ego.  mode 2: acc=(acc+ego)/3.
__global__ void k_epi(float* __restrict__ ego, const float* __restrict__ nk,
                      const float* __restrict__ nrm, float* __restrict__ accF,
                      float* __restrict__ clF, int mode) {
    int t = blockIdx.x * blockDim.x + threadIdx.x;
    if (t >= N_NODES * 16) return;
    int r = t >> 4;
    int idx = t << 2;
    float4 y4 = *(float4*)(ego + idx);
    float4 n4 = *(const float4*)(nk + idx);
    float nv = nrm[r];
    float4 e4;
    {
        float s, q;
        s = (y4.x > 0.f) ? 1.f : ((y4.x < 0.f) ? -1.f : 0.f);
        q = __fdiv_rn(n4.x, nv);
        e4.x = __fadd_rn(y4.x, __fmul_rn(__fmul_rn(s, q), 0.1f));
        s = (y4.y > 0.f) ? 1.f : ((y4.y < 0.f) ? -1.f : 0.f);
        q = __fdiv_rn(n4.y, nv);
        e4.y = __fadd_rn(y4.y, __fmul_rn(__fmul_rn(s, q), 0.1f));
        s = (y4.z > 0.f) ? 1.f : ((y4.z < 0.f) ? -1.f : 0.f);
        q = __fdiv_rn(n4.z, nv);
        e4.z = __fadd_rn(y4.z, __fmul_rn(__fmul_rn(s, q), 0.1f));
        s = (y4.w > 0.f) ? 1.f : ((y4.w < 0.f) ? -1.f : 0.f);
        q = __fdiv_rn(n4.w, nv);
        e4.w = __fadd_rn(y4.w, __fmul_rn(__fmul_rn(s, q), 0.1f));
    }
    *(float4*)(ego + idx) = e4;
    if (mode == 0) {
        *(float4*)(accF + idx) = e4;
        *(float4*)(clF + idx) = e4;
    } else if (mode == 1) {
        float4 a = *(float4*)(accF + idx);
        a.x = __fadd_rn(a.x, e4.x);
        a.y = __fadd_rn(a.y, e4.y);
        a.z = __fadd_rn(a.z, e4.z);
        a.w = __fadd_rn(a.w, e4.w);
        *(float4*)(accF + idx) = a;
    } else {
        float4 a = *(float4*)(accF + idx);
        float4 f;
        f.x = __fdiv_rn(__fadd_rn(a.x, e4.x), 3.0f);
        f.y = __fdiv_rn(__fadd_rn(a.y, e4.y), 3.0f);
        f.z = __fdiv_rn(__fadd_rn(a.z, e4.z), 3.0f);
        f.w = __fdiv_rn(__fadd_rn(a.w, e4.w), 3.0f);
        *(float4*)(accF + idx) = f;
    }
}

extern "C" void kernel_launch(void* const* d_in, const int* in_sizes, int n_in,
                              void* d_out, int out_size, void* d_ws, size_t ws_size,
                              hipStream_t stream) {
    if (ws_size < WS_NEED) return;  // workspace too small -> visible failure

    const float* user_emb = (const float*)d_in[0];
    const float* item_emb = (const float*)d_in[1];
    const int*   adj_rows = (const int*)d_in[2];
    const int*   adj_cols = (const int*)d_in[3];
    const float* adj_vals = (const float*)d_in[4];
    const float* noise    = (const float*)d_in[5];

    char* ws = (char*)d_ws;
    float* bufA = (float*)(ws + BUFA_OFF);
    float* bufB = (float*)(ws + BUFB_OFF);
    int*   perm = (int*)(ws + BUFB_OFF);   // aliased: dead before bufB first written
    int2*  cv   = (int2*)(ws + CV_OFF);
    int*   rs   = (int*)(ws + RS_OFF);
    int*   fill = (int*)(ws + FILL_OFF);
    float* nrm  = (float*)(ws + NRM_OFF);
    int*   bsum = (int*)(ws + NRM_OFF);    // aliased: dead before nrm first written

    float* accF = (float*)d_out;                         // final (acc) region
    float* clF  = (float*)d_out + (size_t)N_NODES * EMB; // cl region

    // ego0 = concat(user_emb, item_emb)
    hipMemcpyAsync(bufA, user_emb, (size_t)USER_NUM * EMB * sizeof(float),
                   hipMemcpyDeviceToDevice, stream);
    hipMemcpyAsync(bufA + (size_t)USER_NUM * EMB, item_emb,
                   (size_t)(N_NODES - USER_NUM) * EMB * sizeof(float),
                   hipMemcpyDeviceToDevice, stream);

    // ---- stable CSR build ----
    hipMemsetAsync(fill, 0, N_NODES * sizeof(int), stream);
    k_hist<<<(N_EDGES + 255) / 256, 256, 0, stream>>>(adj_rows, fill);
    const int NB = (N_NODES + 1023) / 1024;  // 196
    k_scan1<<<NB, 1024, 0, stream>>>(fill, rs, bsum);
    k_scan2<<<1, 64, 0, stream>>>(bsum, NB);
    k_scan3<<<(N_NODES + 255) / 256, 256, 0, stream>>>(rs, bsum);
    hipMemsetAsync(fill, 0, N_NODES * sizeof(int), stream);
    k_scatter<<<(N_EDGES + 255) / 256, 256, 0, stream>>>(adj_rows, rs, fill, perm);
    k_sort<<<(N_NODES + 255) / 256, 256, 0, stream>>>(rs, perm);
    k_gather<<<(N_EDGES + 255) / 256, 256, 0, stream>>>(perm, adj_cols, adj_vals, cv);

    // ---- 3 layers ----
    const int T16 = N_NODES * 16;
    for (int k = 0; k < 3; ++k) {
        float* x = (k & 1) ? bufB : bufA;
        float* y = (k & 1) ? bufA : bufB;
        const float* nk = noise + (size_t)k * N_NODES * EMB;
        k_spmm<<<(T16 + 255) / 256, 256, 0, stream>>>(rs, cv, x, y);
        k_norm<<<(N_NODES + 127) / 128, 128, 0, stream>>>(nk, nrm);
        k_epi<<<(T16 + 255) / 256, 256, 0, stream>>>(y, nk, nrm, accF, clF, k);
    }
}

// Round 3
// 1901.527 us; speedup vs baseline: 1.2144x; 1.2144x over previous
//
#include <hip/hip_runtime.h>

// GCLSDA encoder: ego=concat(U,I); 3x { ego = A@ego; ego += sign(ego)*nhat*0.1; acc+=ego }
// Outputs: final=acc/3, cl=ego_layer1.
// Numerics: SpMM accumulates per (row,dim) sequentially in ascending edge-index
// order with separate _rn mul/add (matches np.add.at); norm uses numpy
// pairwise-sum 8-accumulator pattern. This exact order passed round 1
// (absmax 1.22e-4) — the CSR build below reproduces the IDENTICAL cv order.
//
// CSR build v2: bucket = row>>8 (782 buckets).
//  A1 k_bcount : per-bucket edge counts, LDS-aggregated.
//  k_scan782   : exclusive scan -> bbase, gcur; rs[N]=E.
//  A2 k_bin    : append {col,val,key} to bucket region (sequential frontiers,
//                compact HBM writes vs random 4B scatter).
//  B  k_build  : one WG per bucket: LDS row-histogram -> rs, scatter to final
//                CSR slot (L2-hot 80KB region), per-row insertion sort by edge
//                index. KEY RECOVERY MUST BE LOGICAL SHIFT: (unsigned)key>>24
//                (signed >> sign-extends for row-local >=128 -> OOB crash, R2).

#define USER_NUM 100000
#define N_NODES  200000
#define EMB      64
#define N_EDGES  6400000
#define NBUCK    782        // ceil(200000/256)
#define CAP      14336      // max edges/bucket on LDS fast path (mu=8192, +68 sigma)
#define EPB      4096       // edges per block in A1/A2

static constexpr size_t BUFA_OFF  = 0;
static constexpr size_t BUFB_OFF  = 51200000;
static constexpr size_t CV_OFF    = 102400000;
static constexpr size_t RS_OFF    = 153600000;
static constexpr size_t SMALL_OFF = 154400016;
static constexpr size_t NRM_OFF   = 155200016;
static constexpr size_t WS_NEED   = 156000016;

// ---- Pass A1: bucket counts ----
__global__ void k_bcount(const int* __restrict__ rows, int* __restrict__ bcnt) {
    __shared__ int h[NBUCK];
    for (int i = threadIdx.x; i < NBUCK; i += 256) h[i] = 0;
    __syncthreads();
    int base = blockIdx.x * EPB;
    for (int k = 0; k < EPB / 256; ++k) {
        int e = base + k * 256 + threadIdx.x;
        if (e < N_EDGES) atomicAdd(&h[rows[e] >> 8], 1);
    }
    __syncthreads();
    for (int i = threadIdx.x; i < NBUCK; i += 256) {
        int c = h[i];
        if (c) atomicAdd(&bcnt[i], c);
    }
}

// ---- scan of 782 bucket counts -> bbase (exclusive), gcur; rs[N]=E ----
__global__ void k_scan782(const int* __restrict__ bcnt, int* __restrict__ bbase,
                          int* __restrict__ gcur, int* __restrict__ rs) {
    __shared__ int s[1024];
    int i = threadIdx.x;
    int v = (i < NBUCK) ? bcnt[i] : 0;
    s[i] = v;
    __syncthreads();
    for (int off = 1; off < 1024; off <<= 1) {
        int t = 0;
        if (i >= off) t = s[i - off];
        __syncthreads();
        s[i] += t;
        __syncthreads();
    }
    if (i < NBUCK) {
        int ex = s[i] - v;
        bbase[i] = ex;
        gcur[i] = ex;
    }
    if (i == 0) rs[N_NODES] = N_EDGES;
}

// ---- Pass A2: bin edges into bucket regions ----
__global__ void k_bin(const int* __restrict__ rows, const int* __restrict__ cols,
                      const float* __restrict__ vals, int* __restrict__ gcur,
                      int4* __restrict__ bins) {
    __shared__ int h[NBUCK];
    __shared__ int gb[NBUCK];
    for (int i = threadIdx.x; i < NBUCK; i += 256) h[i] = 0;
    __syncthreads();
    int base = blockIdx.x * EPB;
    int myr[EPB / 256];
    int myrank[EPB / 256];
    for (int k = 0; k < EPB / 256; ++k) {
        int e = base + k * 256 + threadIdx.x;
        myr[k] = -1;
        if (e < N_EDGES) {
            int r = rows[e];
            myr[k] = r;
            myrank[k] = atomicAdd(&h[r >> 8], 1);
        }
    }
    __syncthreads();
    for (int i = threadIdx.x; i < NBUCK; i += 256) {
        int c = h[i];
        if (c) gb[i] = atomicAdd(&gcur[i], c);
    }
    __syncthreads();
    for (int k = 0; k < EPB / 256; ++k) {
        int e = base + k * 256 + threadIdx.x;
        int r = myr[k];
        if (r >= 0) {
            int b = r >> 8;
            int pos = gb[b] + myrank[k];
            int key = ((r & 255) << 24) | e;   // e < 2^23, row-local in top byte
            bins[pos] = make_int4(cols[e], __float_as_int(vals[e]), key, 0);
        }
    }
}

// ---- Pass B: per-bucket row-grouping + stable (edge-idx) ordering -> cv, rs ----
__global__ __launch_bounds__(256) void k_build(int4* __restrict__ bins,
                                               const int* __restrict__ bcnt,
                                               const int* __restrict__ bbase,
                                               int2* __restrict__ cv,
                                               int* __restrict__ rs) {
    __shared__ int cnt[256];
    __shared__ int start[256];
    __shared__ int cur[256];
    __shared__ int scanbuf[256];
    __shared__ int eRow[CAP];
    int tid = threadIdx.x;
    int b = blockIdx.x;
    int n = bcnt[b];
    int base = bbase[b];
    int rowbase = b << 8;
    cnt[tid] = 0;
    __syncthreads();
    // step 1: per-row-local histogram (LOGICAL shift: rl in [0,255])
    for (int i = tid; i < n; i += 256) {
        unsigned key = (unsigned)bins[base + i].z;
        atomicAdd(&cnt[key >> 24], 1);
    }
    __syncthreads();
    // exclusive scan of cnt -> start
    int v = cnt[tid];
    scanbuf[tid] = v;
    __syncthreads();
    for (int off = 1; off < 256; off <<= 1) {
        int t = 0;
        if (tid >= off) t = scanbuf[tid - off];
        __syncthreads();
        scanbuf[tid] += t;
        __syncthreads();
    }
    start[tid] = scanbuf[tid] - v;
    {
        int row = rowbase + tid;
        if (row < N_NODES) rs[row] = base + start[tid];
    }
    cur[tid] = 0;
    __syncthreads();
    if (n <= CAP) {
        // step 2: scatter to final CSR slot; stash edge-key in LDS
        for (int i = tid; i < n; i += 256) {
            int4 e4 = bins[base + i];
            int rl = (int)((unsigned)e4.z >> 24);
            int p = start[rl] + atomicAdd(&cur[rl], 1);
            cv[base + p] = make_int2(e4.x, e4.y);
            eRow[p] = e4.z;  // same top byte within a row -> signed cmp orders by edge idx
        }
        __syncthreads();
        // step 3: per-row insertion sort by edge key (deterministic final order)
        int c = cnt[tid];
        if (c > 1) {
            int s0 = start[tid];
            int s1 = s0 + c;
            for (int i = s0 + 1; i < s1; ++i) {
                int ke = eRow[i];
                int2 kv = cv[base + i];
                int j = i - 1;
                while (j >= s0 && eRow[j] > ke) {
                    eRow[j + 1] = eRow[j];
                    cv[base + j + 1] = cv[base + j];
                    --j;
                }
                eRow[j + 1] = ke;
                cv[base + j + 1] = kv;
            }
        }
    } else {
        // overflow fallback (statistically unreachable): keys in bins[].w
        for (int i = tid; i < n; i += 256) {
            int4 e4 = bins[base + i];
            int rl = (int)((unsigned)e4.z >> 24);
            int p = start[rl] + atomicAdd(&cur[rl], 1);
            cv[base + p] = make_int2(e4.x, e4.y);
            bins[base + p].w = e4.z;
        }
        __syncthreads();
        int c = cnt[tid];
        if (c > 1) {
            int s0 = start[tid];
            int s1 = s0 + c;
            for (int i = s0 + 1; i < s1; ++i) {
                int ke = bins[base + i].w;
                int2 kv = cv[base + i];
                int j = i - 1;
                while (j >= s0 && bins[base + j].w > ke) {
                    bins[base + j + 1].w = bins[base + j].w;
                    cv[base + j + 1] = cv[base + j];
                    --j;
                }
                bins[base + j + 1].w = ke;
                cv[base + j + 1] = kv;
            }
        }
    }
}

// ---- SpMM: one thread per (row, 4-dim group); ascending-edge sequential adds ----
__global__ void k_spmm(const int* __restrict__ rs, const int2* __restrict__ cv,
                       const float* __restrict__ x, float* __restrict__ y) {
    int t = blockIdx.x * blockDim.x + threadIdx.x;
    if (t >= N_NODES * 16) return;
    int r = t >> 4;
    int c = (t & 15) << 2;
    int j0 = rs[r], j1 = rs[r + 1];
    float a0 = 0.f, a1 = 0.f, a2 = 0.f, a3 = 0.f;
    if (j0 < j1) {
        int2 cvc = cv[j0];
        float4 xv = *(const float4*)(x + cvc.x * EMB + c);
        for (int j = j0; j < j1; ++j) {
            int2 cvn = cvc;
            float4 xn = xv;
            if (j + 1 < j1) {
                cvn = cv[j + 1];
                xn = *(const float4*)(x + cvn.x * EMB + c);
            }
            float v = __int_as_float(cvc.y);
            a0 = __fadd_rn(a0, __fmul_rn(v, xv.x));
            a1 = __fadd_rn(a1, __fmul_rn(v, xv.y));
            a2 = __fadd_rn(a2, __fmul_rn(v, xv.z));
            a3 = __fadd_rn(a3, __fmul_rn(v, xv.w));
            cvc = cvn;
            xv = xn;
        }
    }
    *(float4*)(y + r * EMB + c) = make_float4(a0, a1, a2, a3);
}

// ---- per-row L2 norm of noise, numpy pairwise order (8 accumulators, n=64) ----
__global__ void k_norm(const float* __restrict__ nk, float* __restrict__ nrm) {
    __shared__ float tile[2][64 * 65];
    int wave = threadIdx.x >> 6;
    int lane = threadIdx.x & 63;
    int base = blockIdx.x * 128 + wave * 64;
    for (int rr = 0; rr < 64; ++rr) {
        int row = base + rr;
        float v = 0.f;
        if (row < N_NODES) v = nk[row * EMB + lane];
        tile[wave][rr * 65 + lane] = v;
    }
    __syncthreads();
    int row = base + lane;
    if (row < N_NODES) {
        const float* tp = &tile[wave][lane * 65];
        float rj[8];
        #pragma unroll
        for (int j = 0; j < 8; ++j) {
            float xj = tp[j];
            rj[j] = __fmul_rn(xj, xj);
        }
        #pragma unroll
        for (int i = 8; i < 64; i += 8) {
            #pragma unroll
            for (int j = 0; j < 8; ++j) {
                float xj = tp[i + j];
                rj[j] = __fadd_rn(rj[j], __fmul_rn(xj, xj));
            }
        }
        float s01 = __fadd_rn(rj[0], rj[1]);
        float s23 = __fadd_rn(rj[2], rj[3]);
        float s45 = __fadd_rn(rj[4], rj[5]);
        float s67 = __fadd_rn(rj[6], rj[7]);
        float ss = __fadd_rn(__fadd_rn(s01, s23), __fadd_rn(s45, s67));
        float nv = __fsqrt_rn(ss);
        nv = fmaxf(nv, 1e-12f);
        nrm[row] = nv;
    }
}

// ---- epilogue: perturb, acc update, cl capture ----
__global__ void k_epi(float* __restrict__ ego, const float* __restrict__ nk,
                      const float* __restrict__ nrm, float* __restrict__ accF,
                      float* __restrict__ clF, int mode) {
    int t = blockIdx.x * blockDim.x + threadIdx.x;
    if (t >= N_NODES * 16) return;
    int r = t >> 4;
    int idx = t << 2;
    float4 y4 = *(float4*)(ego + idx);
    float4 n4 = *(const float4*)(nk + idx);
    float nv = nrm[r];
    float4 e4;
    {
        float s, q;
        s = (y4.x > 0.f) ? 1.f : ((y4.x < 0.f) ? -1.f : 0.f);
        q = __fdiv_rn(n4.x, nv);
        e4.x = __fadd_rn(y4.x, __fmul_rn(__fmul_rn(s, q), 0.1f));
        s = (y4.y > 0.f) ? 1.f : ((y4.y < 0.f) ? -1.f : 0.f);
        q = __fdiv_rn(n4.y, nv);
        e4.y = __fadd_rn(y4.y, __fmul_rn(__fmul_rn(s, q), 0.1f));
        s = (y4.z > 0.f) ? 1.f : ((y4.z < 0.f) ? -1.f : 0.f);
        q = __fdiv_rn(n4.z, nv);
        e4.z = __fadd_rn(y4.z, __fmul_rn(__fmul_rn(s, q), 0.1f));
        s = (y4.w > 0.f) ? 1.f : ((y4.w < 0.f) ? -1.f : 0.f);
        q = __fdiv_rn(n4.w, nv);
        e4.w = __fadd_rn(y4.w, __fmul_rn(__fmul_rn(s, q), 0.1f));
    }
    *(float4*)(ego + idx) = e4;
    if (mode == 0) {
        *(float4*)(accF + idx) = e4;
        *(float4*)(clF + idx) = e4;
    } else if (mode == 1) {
        float4 a = *(float4*)(accF + idx);
        a.x = __fadd_rn(a.x, e4.x);
        a.y = __fadd_rn(a.y, e4.y);
        a.z = __fadd_rn(a.z, e4.z);
        a.w = __fadd_rn(a.w, e4.w);
        *(float4*)(accF + idx) = a;
    } else {
        float4 a = *(float4*)(accF + idx);
        float4 f;
        f.x = __fdiv_rn(__fadd_rn(a.x, e4.x), 3.0f);
        f.y = __fdiv_rn(__fadd_rn(a.y, e4.y), 3.0f);
        f.z = __fdiv_rn(__fadd_rn(a.z, e4.z), 3.0f);
        f.w = __fdiv_rn(__fadd_rn(a.w, e4.w), 3.0f);
        *(float4*)(accF + idx) = f;
    }
}

extern "C" void kernel_launch(void* const* d_in, const int* in_sizes, int n_in,
                              void* d_out, int out_size, void* d_ws, size_t ws_size,
                              hipStream_t stream) {
    if (ws_size < WS_NEED) return;

    const float* user_emb = (const float*)d_in[0];
    const float* item_emb = (const float*)d_in[1];
    const int*   adj_rows = (const int*)d_in[2];
    const int*   adj_cols = (const int*)d_in[3];
    const float* adj_vals = (const float*)d_in[4];
    const float* noise    = (const float*)d_in[5];

    char* ws = (char*)d_ws;
    float* bufA = (float*)(ws + BUFA_OFF);
    float* bufB = (float*)(ws + BUFB_OFF);
    int4*  bins = (int4*)(ws + BUFA_OFF);   // aliased: dead before ego buffers used
    int2*  cv   = (int2*)(ws + CV_OFF);
    int*   rs   = (int*)(ws + RS_OFF);
    int*   bcnt = (int*)(ws + SMALL_OFF);
    int*   bbase= (int*)(ws + SMALL_OFF + 3200);
    int*   gcur = (int*)(ws + SMALL_OFF + 6400);
    float* nrm  = (float*)(ws + NRM_OFF);

    float* accF = (float*)d_out;
    float* clF  = (float*)d_out + (size_t)N_NODES * EMB;

    // ---- CSR build (must precede ego memcpys: bins aliases bufA/bufB) ----
    hipMemsetAsync(bcnt, 0, NBUCK * sizeof(int), stream);
    const int NBLK = (N_EDGES + EPB - 1) / EPB;  // 1563
    k_bcount<<<NBLK, 256, 0, stream>>>(adj_rows, bcnt);
    k_scan782<<<1, 1024, 0, stream>>>(bcnt, bbase, gcur, rs);
    k_bin<<<NBLK, 256, 0, stream>>>(adj_rows, adj_cols, adj_vals, gcur, bins);
    k_build<<<NBUCK, 256, 0, stream>>>(bins, bcnt, bbase, cv, rs);

    // ego0 = concat(user_emb, item_emb)
    hipMemcpyAsync(bufA, user_emb, (size_t)USER_NUM * EMB * sizeof(float),
                   hipMemcpyDeviceToDevice, stream);
    hipMemcpyAsync(bufA + (size_t)USER_NUM * EMB, item_emb,
                   (size_t)(N_NODES - USER_NUM) * EMB * sizeof(float),
                   hipMemcpyDeviceToDevice, stream);

    // ---- 3 layers ----
    const int T16 = N_NODES * 16;
    for (int k = 0; k < 3; ++k) {
        float* x = (k & 1) ? bufB : bufA;
        float* y = (k & 1) ? bufA : bufB;
        const float* nk = noise + (size_t)k * N_NODES * EMB;
        k_spmm<<<(T16 + 255) / 256, 256, 0, stream>>>(rs, cv, x, y);
        k_norm<<<(N_NODES + 127) / 128, 128, 0, stream>>>(nk, nrm);
        k_epi<<<(T16 + 255) / 256, 256, 0, stream>>>(y, nk, nrm, accF, clF, k);
    }
}